// Round 5
// baseline (552.826 us; speedup 1.0000x reference)
//
#include <hip/hip_runtime.h>
#include <hip/hip_bf16.h>
#include <math.h>

#define HIDDEN 2048
#define NHEADS 16
#define HEADD  128
#define BB     2
#define LL     2048
#define MM     (BB*LL)   // 4096 rows

typedef __attribute__((ext_vector_type(8))) short bf16x8;
typedef __attribute__((ext_vector_type(4))) float f32x4;

#define MFMA16(a,b,c) __builtin_amdgcn_mfma_f32_16x16x32_bf16((a),(b),(c),0,0,0)

__device__ __forceinline__ unsigned short f2bf(float x) {
  unsigned u = __float_as_uint(x);
  u = (u + 0x7fffu + ((u >> 16) & 1u)) >> 16;   // RNE
  return (unsigned short)u;
}

__device__ __forceinline__ bf16x8 pack8(float4 a, float4 b) {
  bf16x8 r;
  r[0]=(short)f2bf(a.x); r[1]=(short)f2bf(a.y); r[2]=(short)f2bf(a.z); r[3]=(short)f2bf(a.w);
  r[4]=(short)f2bf(b.x); r[5]=(short)f2bf(b.y); r[6]=(short)f2bf(b.z); r[7]=(short)f2bf(b.w);
  return r;
}

// ---------------------------------------------------------------------------
// GEMM core: C[128 x 128] tile of A[M][2048] x B[N][2048]^T (B row-major-K
// bf16). A is fp32 (cast during staging) or bf16, per template.
// Reg-staged LDS; 2 barriers / K-step. 4 waves; wave w: rows w*32..+31.
// (unchanged — validated)
// ---------------------------------------------------------------------------
template <bool A_IS_F32>
__device__ __forceinline__ void gemm_core_128(
    const void* __restrict__ Aptr, const unsigned short* __restrict__ B,
    int bm, int bn, f32x4 (&acc)[2][8],
    unsigned short* As, unsigned short* Bs) {
  const int t = threadIdx.x, w = t >> 6, l = t & 63;
  const int lo = l & 15, hi = l >> 4;
  const int K = 2048;
  const int r0 = t >> 2, kq = t & 3;   // staging chunk: rows r0, r0+64; k-chunk kq

#pragma unroll 1
  for (int k0 = 0; k0 < K; k0 += 32) {
#pragma unroll
    for (int h = 0; h < 2; h++) {
      const int row = r0 + h*64;
      bf16x8 av;
      if (A_IS_F32) {
        const float* s = (const float*)Aptr + (size_t)(bm + row)*K + k0 + kq*8;
        av = pack8(*(const float4*)s, *(const float4*)(s + 4));
      } else {
        av = *(const bf16x8*)((const unsigned short*)Aptr +
                              (size_t)(bm + row)*K + k0 + kq*8);
      }
      *(bf16x8*)(As + row*32 + kq*8) = av;
      *(bf16x8*)(Bs + row*32 + kq*8) =
          *(const bf16x8*)(B + (size_t)(bn + row)*K + k0 + kq*8);
    }
    __syncthreads();

    bf16x8 af[2], bfr[8];
#pragma unroll
    for (int m = 0; m < 2; m++)
      af[m] = *(const bf16x8*)(As + (w*32 + m*16 + lo)*32 + hi*8);
#pragma unroll
    for (int n = 0; n < 8; n++)
      bfr[n] = *(const bf16x8*)(Bs + (n*16 + lo)*32 + hi*8);
#pragma unroll
    for (int n = 0; n < 8; n++)
#pragma unroll
      for (int m = 0; m < 2; m++)
        acc[m][n] = MFMA16(af[m], bfr[n], acc[m][n]);
    __syncthreads();
  }
}

// ---------------------------------------------------------------------------
// QKV GEMM (A = fp32 hidden_states, cast in staging) + fused RoPE/scale.
// grid.x = 18 n-tiles: 0..15 -> q head tiles, 16 -> k, 17 -> v(->VT).
// ---------------------------------------------------------------------------
__global__ __launch_bounds__(256) void gemm_qkv(
    const float* __restrict__ hs,             // [4096][2048] fp32
    const unsigned short* __restrict__ WT,    // [2304][2048] bf16 (Wq^T|Wk^T|Wv^T)
    const int* __restrict__ pos,
    unsigned short* __restrict__ qb,          // [4096][2048] bf16 (rope+scale)
    unsigned short* __restrict__ kbf,         // [4096][128]  bf16 (rope)
    unsigned short* __restrict__ vtb) {       // [2][128][2048] bf16 (transposed)
  __shared__ unsigned short As[128*32], Bs[128*32];
  const int nt = blockIdx.x;
  const int bm = blockIdx.y * 128;
  f32x4 acc[2][8];
  const f32x4 zero = {0.f, 0.f, 0.f, 0.f};
#pragma unroll
  for (int m = 0; m < 2; m++)
#pragma unroll
    for (int n = 0; n < 8; n++) acc[m][n] = zero;

  gemm_core_128<true>(hs, WT, bm, nt*128, acc, As, Bs);

  const int t = threadIdx.x, w = t >> 6, l = t & 63;
  const int lo = l & 15, hi = l >> 4;

  if (nt < 17) {
    // RoPE: out[d] = c0*x[d]-s0*x[d+64]; out[d+64] = c1*x[d+64]+s1*x[d]
    const float sc = (nt < 16) ? 0.08838834764831845f : 1.0f;  // fold 1/sqrt(D) into q
    float if0[4];
#pragma unroll
    for (int n = 0; n < 4; n++) {
      int d0 = n*16 + lo;
      if0[n] = __expf(-(float)(d0 & ~1) * 0.07195578415f);     // ln(1e4)/128
    }
#pragma unroll
    for (int m = 0; m < 2; m++)
#pragma unroll
      for (int i = 0; i < 4; i++) {
        int r = bm + w*32 + m*16 + hi*4 + i;
        float p = (float)pos[r & (LL-1)];
#pragma unroll
        for (int n = 0; n < 4; n++) {
          float a0 = p * if0[n], a1 = a0 * 0.01f;
          float s0 = __sinf(a0), c0 = __cosf(a0);
          float s1 = __sinf(a1), c1 = __cosf(a1);
          float x0 = acc[m][n][i], x1 = acc[m][n+4][i];
          float y0 = (c0*x0 - s0*x1) * sc;
          float y1 = (c1*x1 + s1*x0) * sc;
          if (nt < 16) {
            qb[(size_t)r*2048 + nt*128 + n*16 + lo]      = f2bf(y0);
            qb[(size_t)r*2048 + nt*128 + n*16 + lo + 64] = f2bf(y1);
          } else {
            kbf[(size_t)r*128 + n*16 + lo]      = f2bf(y0);
            kbf[(size_t)r*128 + n*16 + lo + 64] = f2bf(y1);
          }
        }
      }
  } else {
    // V tile -> VT[b][d][l] (transposed, bf16)
    const int b = bm >> 11;
#pragma unroll
    for (int m = 0; m < 2; m++)
#pragma unroll
      for (int n = 0; n < 8; n++) {
        int d  = n*16 + lo;
        int r0 = (bm & (LL-1)) + w*32 + m*16 + hi*4;
        ushort4 pk;
        pk.x = f2bf(acc[m][n][0]); pk.y = f2bf(acc[m][n][1]);
        pk.z = f2bf(acc[m][n][2]); pk.w = f2bf(acc[m][n][3]);
        *(ushort4*)(vtb + (size_t)b*HEADD*LL + (size_t)d*LL + r0) = pk;
      }
  }
}

// ---------------------------------------------------------------------------
// Output projection: out[4096][2048] fp32 = ctx(bf16) @ WoT^T
// ---------------------------------------------------------------------------
__global__ __launch_bounds__(256) void gemm_wo(
    const unsigned short* __restrict__ ctx, const unsigned short* __restrict__ WoT,
    float* __restrict__ out) {
  __shared__ unsigned short As[128*32], Bs[128*32];
  const int nt = blockIdx.x, bm = blockIdx.y * 128;
  f32x4 acc[2][8];
  const f32x4 zero = {0.f, 0.f, 0.f, 0.f};
#pragma unroll
  for (int m = 0; m < 2; m++)
#pragma unroll
    for (int n = 0; n < 8; n++) acc[m][n] = zero;

  gemm_core_128<false>(ctx, WoT, bm, nt*128, acc, As, Bs);

  const int t = threadIdx.x, w = t >> 6, l = t & 63;
  const int lo = l & 15, hi = l >> 4;
#pragma unroll
  for (int m = 0; m < 2; m++)
#pragma unroll
    for (int n = 0; n < 8; n++)
#pragma unroll
      for (int i = 0; i < 4; i++)
        out[(size_t)(bm + w*32 + m*16 + hi*4 + i)*2048 + nt*128 + n*16 + lo] =
            acc[m][n][i];
}

// ---------------------------------------------------------------------------
// Flash attention, bf16 MFMA, SWAPPED-S structure (round 5).
// Block = 256 thr = 4 waves; wave owns 32 q-rows; no block barriers.
//
// S^T = K·Q^T: same global loads as before, MFMA operands swapped.
//   D layout: col = lane&15 = q-row (within 16-group), row = hi*4+i = key.
//   => lane holds 16 of 64 keys for ONE q-row: row-max/sum are in-register
//      trees + 2 shfl_xor (16/32) across hi-groups, instead of 8-deep
//      ds_swizzle chains per row-group.
// corr / 1/l redistributed to the O-accumulator lane layout (q = hi*4+i)
// with 4 bpermutes per m-group.
// P packed ushort4 -> wave-private XOR-swizzled LDS (8 ds_write_b64/tile);
// PV side identical to the validated round-4 path.
// ---------------------------------------------------------------------------
__global__ __launch_bounds__(256, 2) void attn_mfma(
    const unsigned short* __restrict__ qb,    // [4096][2048] (scaled, roped)
    const unsigned short* __restrict__ kbf,   // [4096][128]
    const unsigned short* __restrict__ vtb,   // [2][128][2048]
    unsigned short* __restrict__ ctx) {       // [4096][2048] bf16
  __shared__ unsigned short P[4][32*64];      // per-wave P tile, swizzled
  const int t = threadIdx.x, w = t >> 6, l = t & 63;
  const int lo = l & 15, hi = l >> 4;
  const int b = blockIdx.y >> 4, h = blockIdx.y & 15;
  const int q0 = blockIdx.x * 128 + w * 32;

  // Q fragments (serve as MFMA B-operand: col=lo=q, k-elems=hi*8..+7 of d)
  bf16x8 qf[2][4];
  const unsigned short* qrow = qb + ((size_t)(b*LL + q0))*2048 + h*128;
#pragma unroll
  for (int m = 0; m < 2; m++) {
    const unsigned short* r = qrow + (size_t)(m*16 + lo)*2048 + hi*8;
#pragma unroll
    for (int g = 0; g < 4; g++) qf[m][g] = *(const bf16x8*)(r + g*32);
  }

  const unsigned short* kp = kbf + (size_t)b*LL*HEADD;
  const unsigned short* vp = vtb + (size_t)b*HEADD*LL;

  f32x4 o[2][8];
  float mst[2], lst[2];          // per-lane: q-row = m*16 + lo (replicated over hi)
  const f32x4 zero = {0.f, 0.f, 0.f, 0.f};
#pragma unroll
  for (int m = 0; m < 2; m++) {
#pragma unroll
    for (int n = 0; n < 8; n++) o[m][n] = zero;
    mst[m] = -INFINITY; lst[m] = 0.f;
  }

#pragma unroll 1
  for (int kt = 0; kt < LL; kt += 64) {
    // S^T = K Q^T : st[m][j], key = kt + j*16 + hi*4 + i, q = m*16 + lo
    f32x4 st[2][4];
#pragma unroll
    for (int m = 0; m < 2; m++)
#pragma unroll
      for (int j = 0; j < 4; j++) st[m][j] = zero;
#pragma unroll
    for (int j = 0; j < 4; j++)
#pragma unroll
      for (int g = 0; g < 4; g++) {
        bf16x8 kf = *(const bf16x8*)(kp + (size_t)(kt + j*16 + lo)*128 + g*32 + hi*8);
        st[0][j] = MFMA16(kf, qf[0][g], st[0][j]);
        st[1][j] = MFMA16(kf, qf[1][g], st[1][j]);
      }

    // issue V loads: latency hides under softmax
    bf16x8 vf[2][8];
#pragma unroll
    for (int f = 0; f < 2; f++)
#pragma unroll
      for (int n = 0; n < 8; n++)
        vf[f][n] = *(const bf16x8*)(vp + (size_t)(n*16 + lo)*LL + kt + f*32 + hi*8);

    // softmax: lane-local over 16 keys, + 2 shfl_xor across hi-groups
    float corr_o[2][4];
#pragma unroll
    for (int m = 0; m < 2; m++) {
      // in-register max tree over st[m][0..3][0..3]
      float mx[4];
#pragma unroll
      for (int j = 0; j < 4; j++)
        mx[j] = fmaxf(fmaxf(st[m][j][0], st[m][j][1]),
                      fmaxf(st[m][j][2], st[m][j][3]));
      float rm = fmaxf(fmaxf(mx[0], mx[1]), fmaxf(mx[2], mx[3]));
      rm = fmaxf(rm, __shfl_xor(rm, 16, 64));
      rm = fmaxf(rm, __shfl_xor(rm, 32, 64));
      float mo = mst[m];
      float mn = fmaxf(mo, rm);
      float corr = __expf(mo - mn);
      // p = exp(s - mn), in-register sum tree
      float p[4][4];
      float sj[4];
#pragma unroll
      for (int j = 0; j < 4; j++) {
        p[j][0] = __expf(st[m][j][0] - mn); p[j][1] = __expf(st[m][j][1] - mn);
        p[j][2] = __expf(st[m][j][2] - mn); p[j][3] = __expf(st[m][j][3] - mn);
        sj[j] = (p[j][0] + p[j][1]) + (p[j][2] + p[j][3]);
      }
      float rs = (sj[0] + sj[1]) + (sj[2] + sj[3]);
      rs += __shfl_xor(rs, 16, 64);
      rs += __shfl_xor(rs, 32, 64);
      lst[m] = lst[m]*corr + rs;
      mst[m] = mn;
      // pack P: P[q=m*16+lo][key], 8B per j (keys j*16+hi*4..+3), swizzled:
      // logical 16B-chunk cl = j*2 + (hi>>1); physical = cl ^ (lo&7)
      int qrw = m*16 + lo;
#pragma unroll
      for (int j = 0; j < 4; j++) {
        int ch = (j*2 + (hi >> 1)) ^ (lo & 7);
        ushort4 pk;
        pk.x = f2bf(p[j][0]); pk.y = f2bf(p[j][1]);
        pk.z = f2bf(p[j][2]); pk.w = f2bf(p[j][3]);
        *(ushort4*)(&P[w][qrw*64 + ch*8 + (hi & 1)*4]) = pk;
      }
      // redistribute corr to O layout (o rows: q = m*16 + hi*4 + i)
#pragma unroll
      for (int i = 0; i < 4; i++)
        corr_o[m][i] = __shfl(corr, hi*4 + i, 64);
    }
    // O rescale
#pragma unroll
    for (int m = 0; m < 2; m++)
#pragma unroll
      for (int n = 0; n < 8; n++)
#pragma unroll
        for (int i = 0; i < 4; i++) o[m][n][i] *= corr_o[m][i];

    // intra-wave fence: P writes drained before P reads (wave-private buffer)
    asm volatile("s_waitcnt lgkmcnt(0)" ::: "memory");
    __builtin_amdgcn_sched_barrier(0);

    // P A-frags: row = m*16+lo, k-elems = keys f*32+hi*8..+7 (same as r4)
    bf16x8 pa[2][2];
#pragma unroll
    for (int m = 0; m < 2; m++) {
      int row = m*16 + lo;
#pragma unroll
      for (int f = 0; f < 2; f++) {
        int ch = (f*4 + hi) ^ (row & 7);
        pa[m][f] = *(const bf16x8*)(&P[w][row*64 + ch*8]);
      }
    }

    // O += P V  (V already in regs)
#pragma unroll
    for (int f = 0; f < 2; f++)
#pragma unroll
      for (int n = 0; n < 8; n++) {
        o[0][n] = MFMA16(pa[0][f], vf[f][n], o[0][n]);
        o[1][n] = MFMA16(pa[1][f], vf[f][n], o[1][n]);
      }
  }

  // epilogue: redistribute 1/l to O layout, normalize, write ctx bf16
#pragma unroll
  for (int m = 0; m < 2; m++) {
    float invl = 1.0f / lst[m];
    float inv[4];
#pragma unroll
    for (int i = 0; i < 4; i++) inv[i] = __shfl(invl, hi*4 + i, 64);
#pragma unroll
    for (int n = 0; n < 8; n++)
#pragma unroll
      for (int i = 0; i < 4; i++) {
        size_t r = (size_t)(b*LL + q0 + m*16 + hi*4 + i);
        ctx[r*2048 + h*128 + n*16 + lo] = f2bf(o[m][n][i] * inv[i]);
      }
  }
}

// ---------------------------------------------------------------------------
// Transpose-cast all weights: out[n][k] = bf16(in[k][n]).
// ---------------------------------------------------------------------------
__global__ __launch_bounds__(256) void tcast_all(
    const float* __restrict__ Wq, const float* __restrict__ Wk,
    const float* __restrict__ Wv, const float* __restrict__ Wo,
    unsigned short* __restrict__ WTqkv, unsigned short* __restrict__ WoT) {
  __shared__ float T[32][33];
  int bid = blockIdx.x;
  const float* src; unsigned short* dst; int N, rowoff, tile;
  if (bid < 4096)      { src = Wq; dst = WTqkv; N = 2048; rowoff = 0;    tile = bid; }
  else if (bid < 4352) { src = Wk; dst = WTqkv; N = 128;  rowoff = 2048; tile = bid - 4096; }
  else if (bid < 4608) { src = Wv; dst = WTqkv; N = 128;  rowoff = 2176; tile = bid - 4352; }
  else                 { src = Wo; dst = WoT;   N = 2048; rowoff = 0;    tile = bid - 4608; }
  int ntiles = N >> 5;
  int tn = tile & (ntiles - 1), tk = tile / ntiles;
  int tx = threadIdx.x, ty = threadIdx.y;
#pragma unroll
  for (int j = 0; j < 4; j++)
    T[ty + j*8][tx] = src[(size_t)(tk*32 + ty + j*8)*N + tn*32 + tx];
  __syncthreads();
#pragma unroll
  for (int j = 0; j < 4; j++)
    dst[(size_t)(rowoff + tn*32 + ty + j*8)*2048 + tk*32 + tx] = f2bf(T[tx][ty + j*8]);
}

// ---------------------------------------------------------------------------
extern "C" void kernel_launch(void* const* d_in, const int* in_sizes, int n_in,
                              void* d_out, int out_size, void* d_ws, size_t ws_size,
                              hipStream_t stream) {
  const float* hs  = (const float*)d_in[0];
  const int*   pos = (const int*)d_in[1];
  const float* Wq  = (const float*)d_in[2];
  const float* Wk  = (const float*)d_in[3];
  const float* Wv  = (const float*)d_in[4];
  const float* Wo  = (const float*)d_in[5];
  float* out = (float*)d_out;

  char* p = (char*)d_ws;
  unsigned short* WTqkv = (unsigned short*)p; p += (size_t)2304*HIDDEN*2;   //  9.4MB
  unsigned short* WoT   = (unsigned short*)p; p += (size_t)HIDDEN*HIDDEN*2; //  8.4MB
  unsigned short* qb    = (unsigned short*)p; p += (size_t)MM*HIDDEN*2;     // 16.8MB
  unsigned short* kbf   = (unsigned short*)p; p += (size_t)MM*HEADD*2;      //  1.0MB
  unsigned short* vtb   = (unsigned short*)p; p += (size_t)BB*HEADD*LL*2;   //  1.0MB
  unsigned short* ctx   = (unsigned short*)p; p += (size_t)MM*HIDDEN*2;     // 16.8MB
  // total ~53.4MB

  tcast_all<<<8704, dim3(32, 8), 0, stream>>>(Wq, Wk, Wv, Wo, WTqkv, WoT);
  gemm_qkv<<<dim3(18, MM/128), 256, 0, stream>>>(hs, WTqkv, pos, qb, kbf, vtb);
  attn_mfma<<<dim3(LL/128, BB*NHEADS), 256, 0, stream>>>(qb, kbf, vtb, ctx);
  gemm_wo<<<dim3(HIDDEN/128, MM/128), 256, 0, stream>>>(ctx, WoT, out);
}